// Round 16
// baseline (275.148 us; speedup 1.0000x reference)
//
#include <hip/hip_runtime.h>

// LocalSelfAttention2d  B=16,C=256,H=W=64,P=8,HEADS=8,D=32
// Round 16: Q fully in registers via custom d-mapping (R15's PV trick applied
// to QK^T). Phase 2 restructured: wave (hh,qh) computes its OWN Q tiles
// (head hh, d0..31, its 32 pix) + 2 K/V row-tiles x 4 pix-tiles (12 MFMA/kt
// unchanged). d-mapping d(lg,v) = (v>>2)*16 + lg*4 + (v&3):
//   qf = in-register repack of accQ (cvt_pkrtz only)
//   kf = two b64 LDS reads matching the mapping (Kb layout unchanged)
// Qb LDS freed: 63.5KB -> 42KB -> 3 blocks/CU (occupancy cap 50->75%).
// Numerics bit-identical to R15 (same cvt points). prep/K2 unchanged.
// MFMA 16x16x32_f16 (verified): A row=l&15, B col=l&15, D col=l&15(B-idx),
// row=(l>>4)*4+r(A-idx); contraction needs only A/B (lg,v)->k agreement.

typedef _Float16 f16x8 __attribute__((ext_vector_type(8)));
typedef _Float16 f16x4v __attribute__((ext_vector_type(4)));
typedef float    f32x4 __attribute__((ext_vector_type(4)));
typedef unsigned short u16;
typedef unsigned int   u32;
typedef unsigned long long u64;

#define SCALE 0.17677669529663687f  // 1/sqrt(32)
#define QK_S  40    // K [64 pix][40 d]
#define VT_S  72    // V [32 d][72 k]
#define LT_S  264   // transpose staging stride
#define XW_S  264   // x-window LDS stride (528B rows, 2-way banks)
#define OT_S  264   // K2 row-tile stride

__device__ __forceinline__ u16 f2hu(float f) {
    _Float16 h = (_Float16)f; return __builtin_bit_cast(u16, h);
}
__device__ __forceinline__ u64 pack4h(f32x4 v) {
    u32 lo = __builtin_bit_cast(u32, __builtin_amdgcn_cvt_pkrtz(v[0], v[1]));
    u32 hi = __builtin_bit_cast(u32, __builtin_amdgcn_cvt_pkrtz(v[2], v[3]));
    return ((u64)hi << 32) | (u64)lo;
}
__device__ __forceinline__ f16x8 cat44(f16x4v a, f16x4v b) {
    return __builtin_shufflevector(a, b, 0, 1, 2, 3, 4, 5, 6, 7);
}

// ---------------- prep: fused weight-convert + x transpose (R13) ----------------
__global__ __launch_bounds__(512)
void prep(const float* __restrict__ x, const float* __restrict__ wp,
          const float* __restrict__ wo, u16* __restrict__ xtw,
          u16* __restrict__ w16k, u16* __restrict__ wo16k)
{
    __shared__ u16 Lt[64 * LT_S];
    const int bid = blockIdx.x;
    const int tid = threadIdx.x;
    if (bid < 1024) {
        const int y = bid & 63, b = bid >> 6;
        const int yq = y >> 3, py = y & 7;
        const float* xb = x + ((size_t)b * 256) * 4096 + y * 64;
        #pragma unroll
        for (int i = 0; i < 8; ++i) {
            int idx = tid + i * 512;            // 4096 float4s
            int c = idx >> 4, w4 = (idx & 15) << 2;
            float4 v = *(const float4*)(xb + (size_t)c * 4096 + w4);
            float vv[4] = {v.x, v.y, v.z, v.w};
            #pragma unroll
            for (int j = 0; j < 4; ++j) {
                int w = w4 + j;
                Lt[w * LT_S + (c ^ (((w >> 2) & 7) << 3))] = f2hu(vv[j]);
            }
        }
        __syncthreads();
        u16* dst = xtw + (size_t)(b * 64 + yq * 8) * 16384;   // window-row base
        #pragma unroll
        for (int i = 0; i < 4; ++i) {
            int idx = tid + i * 512;            // 2048 f16x8 stores
            int w = idx >> 5, c8 = (idx & 31) << 3;
            f16x8 v = *(const f16x8*)(&Lt[w * LT_S + (c8 ^ (((w >> 2) & 7) << 3))]);
            *(f16x8*)(dst + (w >> 3) * 16384 + (py * 8 + (w & 7)) * 256 + c8) = v;
        }
    } else {
        int idx = (bid - 1024) * 512 + tid;     // 0..262143
        if (idx < 196608) {
            int hq = idx / 98304, o = idx - hq * 98304;
            int kt = o / 12288, o2 = o - kt * 12288;
            int lr = o2 >> 5, cc = o2 & 31;
            int s = lr >> 7, hh = (lr >> 5) & 3, d = lr & 31;
            w16k[idx] = f2hu(wp[(size_t)(s * 256 + (hq * 4 + hh) * 32 + d) * 256 + kt * 32 + cc]);
        } else {
            int j = idx - 196608;               // 0..65535
            int kt = j >> 13, o2 = j & 8191;
            int row = o2 >> 5, cc = o2 & 31;
            wo16k[j] = f2hu(wo[(size_t)row * 256 + kt * 32 + cc]);
        }
    }
}

// ---------------- K1: QKV projection + windowed attention ----------------
__global__ __launch_bounds__(512, 6)
void lsa_qkv_attn_xt(const u16* __restrict__ xtw, const u16* __restrict__ w16k,
                     const float* __restrict__ position, u16* __restrict__ Ows)
{
    // U overlay: phase 1-2: XwL[64][264] = 16896 u16 (33792 B)
    //            phase 3-4: Kb [4][64][40] = 10240 | Vt [4][32][72] = 9216
    __shared__ u16 U[19456];        // 38912 B
    __shared__ float POSL[1024];    // 4096 B: this block's hq-half (4 heads)
    u16* XwL = U;                   // [64][264]
    u16* Kb  = U;                   // [4][64][40]
    u16* Vt  = U + 10240;           // [4][32][72]

    const int tid = threadIdx.x;
    const int hq = blockIdx.x & 1, win = blockIdx.x >> 1, b = blockIdx.y;
    const int w = tid >> 6, m = tid & 15, lg = (tid >> 4) & 3;
    const int hh = w >> 1, qh = w & 1;      // wave role (phase 2 AND phase 4)

    // stage position half + x window (shared operands)
    *(float2*)(&POSL[tid * 2]) = *(const float2*)(position + hq * 1024 + tid * 2);
    {
        const u16* xwin = xtw + (size_t)(b * 64 + win) * 16384;
        #pragma unroll
        for (int i = 0; i < 4; ++i) {
            int g = tid + i * 512;              // 2048 16B-chunks
            *(f16x8*)(XwL + (g >> 5) * XW_S + (g & 31) * 8) = *(const f16x8*)(xwin + g * 8);
        }
    }
    __syncthreads();

    // ---- phase 2: QKV GEMM.
    //  Q: wave (hh,qh) computes head hh, d 0..31 (2 M-tiles) x its 2 pix-tiles.
    //  K/V: wave w owns row-tiles 2w, 2w+1 of the 16 (K=0..7, V=8..15) x all 4 pix-tiles.
    f32x4 accQ[2][2];               // [d-tile t][ntq]
    f32x4 accKV[2][4];              // [j][nt]
    int lrowKV[2], isvKV[2], hhKV[2], d0KV[2];
    {
        const f32x4 z = {0.f, 0.f, 0.f, 0.f};
        #pragma unroll
        for (int t = 0; t < 2; ++t) { accQ[t][0] = z; accQ[t][1] = z; }
        #pragma unroll
        for (int j = 0; j < 2; ++j) {
            #pragma unroll
            for (int nt = 0; nt < 4; ++nt) accKV[j][nt] = z;
            int t2 = 2 * w + j;                 // 0..15
            isvKV[j] = t2 >> 3;                 // 0=K, 1=V
            hhKV[j] = (t2 >> 1) & 3;
            d0KV[j] = (t2 & 1) * 16;
            lrowKV[j] = (1 + isvKV[j]) * 128 + hhKV[j] * 32 + d0KV[j];  // s=1 K, s=2 V
        }
        const u16* wbase = w16k + (size_t)hq * 98304;
        #pragma unroll
        for (int kt = 0; kt < 8; ++kt) {
            f16x8 afq[2], afkv[2], bf[4];
            #pragma unroll
            for (int t = 0; t < 2; ++t)        // Q rows: s=0, head hh, d-tile t
                afq[t] = *(const f16x8*)(wbase + kt * 12288 + (hh * 32 + t * 16 + m) * 32 + lg * 8);
            #pragma unroll
            for (int j = 0; j < 2; ++j)
                afkv[j] = *(const f16x8*)(wbase + kt * 12288 + (lrowKV[j] + m) * 32 + lg * 8);
            #pragma unroll
            for (int nt = 0; nt < 4; ++nt)
                bf[nt] = *(const f16x8*)(XwL + (nt * 16 + m) * XW_S + kt * 32 + lg * 8);
            #pragma unroll
            for (int t = 0; t < 2; ++t)
                #pragma unroll
                for (int n = 0; n < 2; ++n)
                    accQ[t][n] = __builtin_amdgcn_mfma_f32_16x16x32_f16(afq[t], bf[2 * qh + n], accQ[t][n], 0, 0, 0);
            #pragma unroll
            for (int j = 0; j < 2; ++j)
                #pragma unroll
                for (int nt = 0; nt < 4; ++nt)
                    accKV[j][nt] = __builtin_amdgcn_mfma_f32_16x16x32_f16(afkv[j], bf[nt], accKV[j][nt], 0, 0, 0);
        }
    }
    __syncthreads();   // XwL reads done before K/V overlay U

    // ---- phase 3: scatter K/V only (Q stays in registers)
    {
        #pragma unroll
        for (int j = 0; j < 2; ++j) {
            int hhj = hhKV[j], d0j = d0KV[j];
            #pragma unroll
            for (int nt = 0; nt < 4; ++nt) {
                int pix = nt * 16 + m;
                if (isvKV[j] == 0) {
                    *(u64*)(Kb + hhj * 64 * QK_S + pix * QK_S + d0j + lg * 4) = pack4h(accKV[j][nt]);
                } else {
                    #pragma unroll
                    for (int r = 0; r < 4; ++r)
                        Vt[hhj * 32 * VT_S + (d0j + lg * 4 + r) * VT_S + pix] = f2hu(accKV[j][nt][r]);
                }
            }
        }
    }
    __syncthreads();

    // ---- phase 4: attention; Q in registers, P in registers
    {
        const u16* Kh = Kb + hh * 64 * QK_S;
        const u16* Vh = Vt + hh * 32 * VT_S;
        const float* posh = &POSL[hh * 256];

        // qf via d-mapping d(lg,v)=(v>>2)*16+lg*4+(v&3): pure in-register
        f16x8 qf[2];
        #pragma unroll
        for (int qi = 0; qi < 2; ++qi) {
            f16x4v q0 = __builtin_bit_cast(f16x4v, pack4h(accQ[0][qi]));
            f16x4v q1 = __builtin_bit_cast(f16x4v, pack4h(accQ[1][qi]));
            qf[qi] = cat44(q0, q1);
        }
        // kf with matching mapping: two b64 reads per kt
        f16x8 kf[4];
        #pragma unroll
        for (int kt = 0; kt < 4; ++kt) {
            const u16* krow = Kh + (kt * 16 + m) * QK_S + lg * 4;
            f16x4v k0 = *(const f16x4v*)(krow);
            f16x4v k1 = *(const f16x4v*)(krow + 16);
            kf[kt] = cat44(k0, k1);
        }

        const f32x4 z = {0.f, 0.f, 0.f, 0.f};
        f32x4 st[4][2];
        #pragma unroll
        for (int kt = 0; kt < 4; ++kt)
            #pragma unroll
            for (int qi = 0; qi < 2; ++qi)
                st[kt][qi] = __builtin_amdgcn_mfma_f32_16x16x32_f16(kf[kt], qf[qi], z, 0, 0, 0);
        // lane holds S[q=(2qh+qi)*16+m][k=kt*16+lg*4+r]

        float inv[2];
        #pragma unroll
        for (int qi = 0; qi < 2; ++qi) {
            int q = (2 * qh + qi) * 16 + m, qy = q >> 3, qx = q & 7;
            float mx = -1e30f;
            #pragma unroll
            for (int kt = 0; kt < 4; ++kt)
                #pragma unroll
                for (int r = 0; r < 4; ++r) {
                    int k = kt * 16 + lg * 4 + r, ky = k >> 3, kx = k & 7;
                    float t = st[kt][qi][r] * SCALE + posh[(ky - qy + 8) * 16 + (kx - qx + 8)];
                    st[kt][qi][r] = t;
                    mx = fmaxf(mx, t);
                }
            mx = fmaxf(mx, __shfl_xor(mx, 16));
            mx = fmaxf(mx, __shfl_xor(mx, 32));
            float sum = 0.f;
            #pragma unroll
            for (int kt = 0; kt < 4; ++kt)
                #pragma unroll
                for (int r = 0; r < 4; ++r) {
                    float e = __expf(st[kt][qi][r] - mx);
                    st[kt][qi][r] = e; sum += e;
                }
            sum += __shfl_xor(sum, 16);
            sum += __shfl_xor(sum, 32);
            inv[qi] = 1.f / sum;
        }

        // PV with k-mapping k(lg,v) = (2ks+(v>>2))*16 + lg*4 + (v&3) (R15-verified)
        f32x4 ot[2][2];
        ot[0][0] = z; ot[0][1] = z; ot[1][0] = z; ot[1][1] = z;
        #pragma unroll
        for (int ks = 0; ks < 2; ++ks) {
            f16x8 pf[2], vf[2];
            #pragma unroll
            for (int qi = 0; qi < 2; ++qi) {
                f16x4v lo = __builtin_bit_cast(f16x4v, pack4h(st[2 * ks + 0][qi] * inv[qi]));
                f16x4v hi = __builtin_bit_cast(f16x4v, pack4h(st[2 * ks + 1][qi] * inv[qi]));
                pf[qi] = cat44(lo, hi);
            }
            #pragma unroll
            for (int dt = 0; dt < 2; ++dt) {
                const u16* vrow = Vh + (dt * 16 + m) * VT_S + lg * 4;
                f16x4v v0 = *(const f16x4v*)(vrow + (2 * ks + 0) * 16);
                f16x4v v1 = *(const f16x4v*)(vrow + (2 * ks + 1) * 16);
                vf[dt] = cat44(v0, v1);
            }
            #pragma unroll
            for (int qi = 0; qi < 2; ++qi)
                #pragma unroll
                for (int dt = 0; dt < 2; ++dt)
                    ot[qi][dt] = __builtin_amdgcn_mfma_f32_16x16x32_f16(pf[qi], vf[dt], ot[qi][dt], 0, 0, 0);
        }

        // O -> Ows [bw][pix][c] fp16 (lane=c-col, regs=q-rows)
        const size_t obase = (size_t)(b * 64 + win) * 16384;
        const int head = hq * 4 + hh;
        #pragma unroll
        for (int qi = 0; qi < 2; ++qi)
            #pragma unroll
            for (int dt = 0; dt < 2; ++dt) {
                int c = head * 32 + dt * 16 + m;
                #pragma unroll
                for (int r = 0; r < 4; ++r) {
                    int q = (2 * qh + qi) * 16 + lg * 4 + r;
                    Ows[obase + q * 256 + c] = f2hu(ot[qi][dt][r]);
                }
            }
    }
}

// -------- K2: out-projection, ROW-major blocks (unchanged R13) --------
__global__ __launch_bounds__(512, 4)
void lsa_outproj_row(const u16* __restrict__ Ows, const u16* __restrict__ wo16k,
                     const float* __restrict__ b_out, float* __restrict__ out)
{
    __shared__ u16 Ot[64 * OT_S];    // 33792 B [64 px][264 c]

    const int tid = threadIdx.x;
    const int y = blockIdx.x, b = blockIdx.y;
    const int yq = y >> 3, py = y & 7;
    const int w = tid >> 6, m = tid & 15, lg = (tid >> 4) & 3;

    {
        const u16* slab = Ows + (size_t)(b * 64 + yq * 8) * 16384 + (py * 8) * 256;
        #pragma unroll
        for (int i = 0; i < 4; ++i) {
            int g = tid + i * 512;              // 2048 16B-chunks
            int wx = g >> 8, gg = g & 255;
            int lx = gg >> 5, c8 = (gg & 31) << 3;
            f16x8 v = *(const f16x8*)(slab + (size_t)wx * 16384 + lx * 256 + c8);
            *(f16x8*)(Ot + (wx * 8 + lx) * OT_S + c8) = v;
        }
    }
    __syncthreads();

    f32x4 oa[2][4];
    {
        const f32x4 z = {0.f, 0.f, 0.f, 0.f};
        #pragma unroll
        for (int mt = 0; mt < 2; ++mt)
            #pragma unroll
            for (int nt = 0; nt < 4; ++nt) oa[mt][nt] = z;
    }
    #pragma unroll
    for (int kt = 0; kt < 8; ++kt) {
        f16x8 wf[2], of[4];
        #pragma unroll
        for (int mt = 0; mt < 2; ++mt)
            wf[mt] = *(const f16x8*)(wo16k + kt * 8192 + (w * 32 + mt * 16 + m) * 32 + lg * 8);
        #pragma unroll
        for (int nt = 0; nt < 4; ++nt)
            of[nt] = *(const f16x8*)(Ot + (nt * 16 + m) * OT_S + kt * 32 + lg * 8);
        #pragma unroll
        for (int mt = 0; mt < 2; ++mt)
            #pragma unroll
            for (int nt = 0; nt < 4; ++nt)
                oa[mt][nt] = __builtin_amdgcn_mfma_f32_16x16x32_f16(wf[mt], of[nt], oa[mt][nt], 0, 0, 0);
    }
    // write out[b][oc][y][px]: 16 consecutive px per (oc) -> 64B segments
    float* ob = out + (size_t)b * 1048576 + y * 64;
    #pragma unroll
    for (int mt = 0; mt < 2; ++mt)
        #pragma unroll
        for (int nt = 0; nt < 4; ++nt) {
            int px = nt * 16 + m;
            #pragma unroll
            for (int r = 0; r < 4; ++r) {
                int oc = w * 32 + mt * 16 + lg * 4 + r;
                ob[(size_t)oc * 4096 + px] = oa[mt][nt][r] + b_out[oc];
            }
        }
}

extern "C" void kernel_launch(void* const* d_in, const int* in_sizes, int n_in,
                              void* d_out, int out_size, void* d_ws, size_t ws_size,
                              hipStream_t stream) {
    const float* x      = (const float*)d_in[0];
    const float* w_proj = (const float*)d_in[1];
    const float* pos    = (const float*)d_in[2];
    const float* w_out  = (const float*)d_in[3];
    const float* b_out  = (const float*)d_in[4];
    float* out = (float*)d_out;

    // d_ws: [0,32M) x_tw ; +32M w16k (384K) ; wo16k (128K) ; Ows (32M)
    u16* xtw   = (u16*)d_ws;
    u16* w16k  = (u16*)((char*)d_ws + 33554432);
    u16* wo16k = (u16*)((char*)d_ws + 33554432 + 393216);
    u16* Ows   = (u16*)((char*)d_ws + 33554432 + 393216 + 131072);

    prep<<<1536, 512, 0, stream>>>(x, w_proj, w_out, xtw, w16k, wo16k);
    lsa_qkv_attn_xt<<<dim3(128, 16), 512, 0, stream>>>(xtw, w16k, pos, Ows);
    lsa_outproj_row<<<dim3(64, 16), 512, 0, stream>>>(Ows, wo16k, b_out, out);
}

// Round 17
// 112.151 us; speedup vs baseline: 2.4534x; 2.4534x over previous
//
#include <hip/hip_runtime.h>

// LocalSelfAttention2d  B=16,C=256,H=W=64,P=8,HEADS=8,D=32
// Round 17: R16 (Q-in-registers, 43KB LDS, 3 blocks/CU) with the spill bug
// fixed. R16's bf[2*qh+n] was a RUNTIME-indexed register array -> demoted to
// scratch (WRITE_SIZE 33KB->940MB, rule #20). Fix: qh folded into load
// ADDRESSES only; all register arrays statically indexed. Register pressure
// reduced for the 85-VGPR cap (6 waves/EU): bf and kf loaded one-at-a-time.
// Numerics identical to R15/R16 (absmax 0.03125 both).
// MFMA 16x16x32_f16 (verified): A row=l&15, B col=l&15, D col=l&15(B-idx),
// row=(l>>4)*4+r(A-idx); contraction needs only A/B (lg,v)->k agreement.

typedef _Float16 f16x8 __attribute__((ext_vector_type(8)));
typedef _Float16 f16x4v __attribute__((ext_vector_type(4)));
typedef float    f32x4 __attribute__((ext_vector_type(4)));
typedef unsigned short u16;
typedef unsigned int   u32;
typedef unsigned long long u64;

#define SCALE 0.17677669529663687f  // 1/sqrt(32)
#define QK_S  40    // K [64 pix][40 d]
#define VT_S  72    // V [32 d][72 k]
#define LT_S  264   // transpose staging stride
#define XW_S  264   // x-window LDS stride (528B rows, 2-way banks)
#define OT_S  264   // K2 row-tile stride

__device__ __forceinline__ u16 f2hu(float f) {
    _Float16 h = (_Float16)f; return __builtin_bit_cast(u16, h);
}
__device__ __forceinline__ u64 pack4h(f32x4 v) {
    u32 lo = __builtin_bit_cast(u32, __builtin_amdgcn_cvt_pkrtz(v[0], v[1]));
    u32 hi = __builtin_bit_cast(u32, __builtin_amdgcn_cvt_pkrtz(v[2], v[3]));
    return ((u64)hi << 32) | (u64)lo;
}
__device__ __forceinline__ f16x8 cat44(f16x4v a, f16x4v b) {
    return __builtin_shufflevector(a, b, 0, 1, 2, 3, 4, 5, 6, 7);
}

// ---------------- prep: fused weight-convert + x transpose (R13) ----------------
__global__ __launch_bounds__(512)
void prep(const float* __restrict__ x, const float* __restrict__ wp,
          const float* __restrict__ wo, u16* __restrict__ xtw,
          u16* __restrict__ w16k, u16* __restrict__ wo16k)
{
    __shared__ u16 Lt[64 * LT_S];
    const int bid = blockIdx.x;
    const int tid = threadIdx.x;
    if (bid < 1024) {
        const int y = bid & 63, b = bid >> 6;
        const int yq = y >> 3, py = y & 7;
        const float* xb = x + ((size_t)b * 256) * 4096 + y * 64;
        #pragma unroll
        for (int i = 0; i < 8; ++i) {
            int idx = tid + i * 512;            // 4096 float4s
            int c = idx >> 4, w4 = (idx & 15) << 2;
            float4 v = *(const float4*)(xb + (size_t)c * 4096 + w4);
            float vv[4] = {v.x, v.y, v.z, v.w};
            #pragma unroll
            for (int j = 0; j < 4; ++j) {
                int w = w4 + j;
                Lt[w * LT_S + (c ^ (((w >> 2) & 7) << 3))] = f2hu(vv[j]);
            }
        }
        __syncthreads();
        u16* dst = xtw + (size_t)(b * 64 + yq * 8) * 16384;   // window-row base
        #pragma unroll
        for (int i = 0; i < 4; ++i) {
            int idx = tid + i * 512;            // 2048 f16x8 stores
            int w = idx >> 5, c8 = (idx & 31) << 3;
            f16x8 v = *(const f16x8*)(&Lt[w * LT_S + (c8 ^ (((w >> 2) & 7) << 3))]);
            *(f16x8*)(dst + (w >> 3) * 16384 + (py * 8 + (w & 7)) * 256 + c8) = v;
        }
    } else {
        int idx = (bid - 1024) * 512 + tid;     // 0..262143
        if (idx < 196608) {
            int hq = idx / 98304, o = idx - hq * 98304;
            int kt = o / 12288, o2 = o - kt * 12288;
            int lr = o2 >> 5, cc = o2 & 31;
            int s = lr >> 7, hh = (lr >> 5) & 3, d = lr & 31;
            w16k[idx] = f2hu(wp[(size_t)(s * 256 + (hq * 4 + hh) * 32 + d) * 256 + kt * 32 + cc]);
        } else {
            int j = idx - 196608;               // 0..65535
            int kt = j >> 13, o2 = j & 8191;
            int row = o2 >> 5, cc = o2 & 31;
            wo16k[j] = f2hu(wo[(size_t)row * 256 + kt * 32 + cc]);
        }
    }
}

// ---------------- K1: QKV projection + windowed attention ----------------
__global__ __launch_bounds__(512, 6)
void lsa_qkv_attn_xt(const u16* __restrict__ xtw, const u16* __restrict__ w16k,
                     const float* __restrict__ position, u16* __restrict__ Ows)
{
    // U overlay: phase 1-2: XwL[64][264] = 16896 u16 (33792 B)
    //            phase 3-4: Kb [4][64][40] = 10240 | Vt [4][32][72] = 9216
    __shared__ u16 U[19456];        // 38912 B
    __shared__ float POSL[1024];    // 4096 B: this block's hq-half (4 heads)
    u16* XwL = U;                   // [64][264]
    u16* Kb  = U;                   // [4][64][40]
    u16* Vt  = U + 10240;           // [4][32][72]

    const int tid = threadIdx.x;
    const int hq = blockIdx.x & 1, win = blockIdx.x >> 1, b = blockIdx.y;
    const int w = tid >> 6, m = tid & 15, lg = (tid >> 4) & 3;
    const int hh = w >> 1, qh = w & 1;      // wave role (phase 2 AND phase 4)

    // stage position half + x window (shared operands)
    *(float2*)(&POSL[tid * 2]) = *(const float2*)(position + hq * 1024 + tid * 2);
    {
        const u16* xwin = xtw + (size_t)(b * 64 + win) * 16384;
        #pragma unroll
        for (int i = 0; i < 4; ++i) {
            int g = tid + i * 512;              // 2048 16B-chunks
            *(f16x8*)(XwL + (g >> 5) * XW_S + (g & 31) * 8) = *(const f16x8*)(xwin + g * 8);
        }
    }
    __syncthreads();

    // ---- phase 2: QKV GEMM.
    //  Q: wave (hh,qh) computes head hh, d 0..31 (2 M-tiles) x ITS 2 pix-tiles
    //     (qh in the ADDRESS, never an array index - rule #20).
    //  K/V: wave w owns row-tiles 2w, 2w+1 of 16 (K=0..7, V=8..15) x 4 pix-tiles.
    f32x4 accQ[2][2];               // [d-tile t][n]
    f32x4 accKV[2][4];              // [j][nt]
    int lrowKV[2], isvKV[2], hhKV[2], d0KV[2];
    {
        const f32x4 z = {0.f, 0.f, 0.f, 0.f};
        #pragma unroll
        for (int t = 0; t < 2; ++t) { accQ[t][0] = z; accQ[t][1] = z; }
        #pragma unroll
        for (int j = 0; j < 2; ++j) {
            #pragma unroll
            for (int nt = 0; nt < 4; ++nt) accKV[j][nt] = z;
            int t2 = 2 * w + j;                 // 0..15
            isvKV[j] = t2 >> 3;                 // 0=K, 1=V
            hhKV[j] = (t2 >> 1) & 3;
            d0KV[j] = (t2 & 1) * 16;
            lrowKV[j] = (1 + isvKV[j]) * 128 + hhKV[j] * 32 + d0KV[j];  // s=1 K, s=2 V
        }
        const u16* wbase = w16k + (size_t)hq * 98304;
        #pragma unroll
        for (int kt = 0; kt < 8; ++kt) {
            f16x8 afq[2], afkv[2];
            #pragma unroll
            for (int t = 0; t < 2; ++t)        // Q rows: s=0, head hh, d-tile t
                afq[t] = *(const f16x8*)(wbase + kt * 12288 + (hh * 32 + t * 16 + m) * 32 + lg * 8);
            #pragma unroll
            for (int j = 0; j < 2; ++j)
                afkv[j] = *(const f16x8*)(wbase + kt * 12288 + (lrowKV[j] + m) * 32 + lg * 8);
            // K/V: bf loaded one-at-a-time (live range 1, not 4)
            #pragma unroll
            for (int nt = 0; nt < 4; ++nt) {
                f16x8 bf = *(const f16x8*)(XwL + (nt * 16 + m) * XW_S + kt * 32 + lg * 8);
                accKV[0][nt] = __builtin_amdgcn_mfma_f32_16x16x32_f16(afkv[0], bf, accKV[0][nt], 0, 0, 0);
                accKV[1][nt] = __builtin_amdgcn_mfma_f32_16x16x32_f16(afkv[1], bf, accKV[1][nt], 0, 0, 0);
            }
            // Q: re-load this wave's 2 pix-tiles (qh in address only)
            #pragma unroll
            for (int n = 0; n < 2; ++n) {
                f16x8 bq = *(const f16x8*)(XwL + ((2 * qh + n) * 16 + m) * XW_S + kt * 32 + lg * 8);
                accQ[0][n] = __builtin_amdgcn_mfma_f32_16x16x32_f16(afq[0], bq, accQ[0][n], 0, 0, 0);
                accQ[1][n] = __builtin_amdgcn_mfma_f32_16x16x32_f16(afq[1], bq, accQ[1][n], 0, 0, 0);
            }
        }
    }
    __syncthreads();   // XwL reads done before K/V overlay U

    // ---- phase 3: scatter K/V only (Q stays in registers)
    {
        #pragma unroll
        for (int j = 0; j < 2; ++j) {
            int hhj = hhKV[j], d0j = d0KV[j];
            #pragma unroll
            for (int nt = 0; nt < 4; ++nt) {
                int pix = nt * 16 + m;
                if (isvKV[j] == 0) {
                    *(u64*)(Kb + hhj * 64 * QK_S + pix * QK_S + d0j + lg * 4) = pack4h(accKV[j][nt]);
                } else {
                    #pragma unroll
                    for (int r = 0; r < 4; ++r)
                        Vt[hhj * 32 * VT_S + (d0j + lg * 4 + r) * VT_S + pix] = f2hu(accKV[j][nt][r]);
                }
            }
        }
    }
    __syncthreads();

    // ---- phase 4: attention; Q in registers, P in registers
    {
        const u16* Kh = Kb + hh * 64 * QK_S;
        const u16* Vh = Vt + hh * 32 * VT_S;
        const float* posh = &POSL[hh * 256];

        // qf via d-mapping d(lg,v)=(v>>2)*16+lg*4+(v&3): pure in-register
        f16x8 qf[2];
        #pragma unroll
        for (int qi = 0; qi < 2; ++qi) {
            f16x4v q0 = __builtin_bit_cast(f16x4v, pack4h(accQ[0][qi]));
            f16x4v q1 = __builtin_bit_cast(f16x4v, pack4h(accQ[1][qi]));
            qf[qi] = cat44(q0, q1);
        }

        const f32x4 z = {0.f, 0.f, 0.f, 0.f};
        f32x4 st[4][2];
        // kf loaded per-kt (same d-mapping), live range 1
        #pragma unroll
        for (int kt = 0; kt < 4; ++kt) {
            const u16* krow = Kh + (kt * 16 + m) * QK_S + lg * 4;
            f16x8 kf = cat44(*(const f16x4v*)(krow), *(const f16x4v*)(krow + 16));
            st[kt][0] = __builtin_amdgcn_mfma_f32_16x16x32_f16(kf, qf[0], z, 0, 0, 0);
            st[kt][1] = __builtin_amdgcn_mfma_f32_16x16x32_f16(kf, qf[1], z, 0, 0, 0);
        }
        // lane holds S[q=(2qh+qi)*16+m][k=kt*16+lg*4+r]

        float inv[2];
        #pragma unroll
        for (int qi = 0; qi < 2; ++qi) {
            int q = (2 * qh + qi) * 16 + m, qy = q >> 3, qx = q & 7;
            float mx = -1e30f;
            #pragma unroll
            for (int kt = 0; kt < 4; ++kt)
                #pragma unroll
                for (int r = 0; r < 4; ++r) {
                    int k = kt * 16 + lg * 4 + r, ky = k >> 3, kx = k & 7;
                    float t = st[kt][qi][r] * SCALE + posh[(ky - qy + 8) * 16 + (kx - qx + 8)];
                    st[kt][qi][r] = t;
                    mx = fmaxf(mx, t);
                }
            mx = fmaxf(mx, __shfl_xor(mx, 16));
            mx = fmaxf(mx, __shfl_xor(mx, 32));
            float sum = 0.f;
            #pragma unroll
            for (int kt = 0; kt < 4; ++kt)
                #pragma unroll
                for (int r = 0; r < 4; ++r) {
                    float e = __expf(st[kt][qi][r] - mx);
                    st[kt][qi][r] = e; sum += e;
                }
            sum += __shfl_xor(sum, 16);
            sum += __shfl_xor(sum, 32);
            inv[qi] = 1.f / sum;
        }

        // PV with k-mapping k(lg,v) = (2ks+(v>>2))*16 + lg*4 + (v&3) (R15-verified)
        f32x4 ot[2][2];
        ot[0][0] = z; ot[0][1] = z; ot[1][0] = z; ot[1][1] = z;
        #pragma unroll
        for (int ks = 0; ks < 2; ++ks) {
            f16x8 pf[2], vf[2];
            #pragma unroll
            for (int qi = 0; qi < 2; ++qi) {
                f16x4v lo = __builtin_bit_cast(f16x4v, pack4h(st[2 * ks + 0][qi] * inv[qi]));
                f16x4v hi = __builtin_bit_cast(f16x4v, pack4h(st[2 * ks + 1][qi] * inv[qi]));
                pf[qi] = cat44(lo, hi);
            }
            #pragma unroll
            for (int dt = 0; dt < 2; ++dt) {
                const u16* vrow = Vh + (dt * 16 + m) * VT_S + lg * 4;
                f16x4v v0 = *(const f16x4v*)(vrow + (2 * ks + 0) * 16);
                f16x4v v1 = *(const f16x4v*)(vrow + (2 * ks + 1) * 16);
                vf[dt] = cat44(v0, v1);
            }
            #pragma unroll
            for (int qi = 0; qi < 2; ++qi)
                #pragma unroll
                for (int dt = 0; dt < 2; ++dt)
                    ot[qi][dt] = __builtin_amdgcn_mfma_f32_16x16x32_f16(pf[qi], vf[dt], ot[qi][dt], 0, 0, 0);
        }

        // O -> Ows [bw][pix][c] fp16 (lane=c-col, regs=q-rows)
        const size_t obase = (size_t)(b * 64 + win) * 16384;
        const int head = hq * 4 + hh;
        #pragma unroll
        for (int qi = 0; qi < 2; ++qi)
            #pragma unroll
            for (int dt = 0; dt < 2; ++dt) {
                int c = head * 32 + dt * 16 + m;
                #pragma unroll
                for (int r = 0; r < 4; ++r) {
                    int q = (2 * qh + qi) * 16 + lg * 4 + r;
                    Ows[obase + q * 256 + c] = f2hu(ot[qi][dt][r]);
                }
            }
    }
}

// -------- K2: out-projection, ROW-major blocks (unchanged R13) --------
__global__ __launch_bounds__(512, 4)
void lsa_outproj_row(const u16* __restrict__ Ows, const u16* __restrict__ wo16k,
                     const float* __restrict__ b_out, float* __restrict__ out)
{
    __shared__ u16 Ot[64 * OT_S];    // 33792 B [64 px][264 c]

    const int tid = threadIdx.x;
    const int y = blockIdx.x, b = blockIdx.y;
    const int yq = y >> 3, py = y & 7;
    const int w = tid >> 6, m = tid & 15, lg = (tid >> 4) & 3;

    {
        const u16* slab = Ows + (size_t)(b * 64 + yq * 8) * 16384 + (py * 8) * 256;
        #pragma unroll
        for (int i = 0; i < 4; ++i) {
            int g = tid + i * 512;              // 2048 16B-chunks
            int wx = g >> 8, gg = g & 255;
            int lx = gg >> 5, c8 = (gg & 31) << 3;
            f16x8 v = *(const f16x8*)(slab + (size_t)wx * 16384 + lx * 256 + c8);
            *(f16x8*)(Ot + (wx * 8 + lx) * OT_S + c8) = v;
        }
    }
    __syncthreads();

    f32x4 oa[2][4];
    {
        const f32x4 z = {0.f, 0.f, 0.f, 0.f};
        #pragma unroll
        for (int mt = 0; mt < 2; ++mt)
            #pragma unroll
            for (int nt = 0; nt < 4; ++nt) oa[mt][nt] = z;
    }
    #pragma unroll
    for (int kt = 0; kt < 8; ++kt) {
        f16x8 wf[2], of[4];
        #pragma unroll
        for (int mt = 0; mt < 2; ++mt)
            wf[mt] = *(const f16x8*)(wo16k + kt * 8192 + (w * 32 + mt * 16 + m) * 32 + lg * 8);
        #pragma unroll
        for (int nt = 0; nt < 4; ++nt)
            of[nt] = *(const f16x8*)(Ot + (nt * 16 + m) * OT_S + kt * 32 + lg * 8);
        #pragma unroll
        for (int mt = 0; mt < 2; ++mt)
            #pragma unroll
            for (int nt = 0; nt < 4; ++nt)
                oa[mt][nt] = __builtin_amdgcn_mfma_f32_16x16x32_f16(wf[mt], of[nt], oa[mt][nt], 0, 0, 0);
    }
    // write out[b][oc][y][px]: 16 consecutive px per (oc) -> 64B segments
    float* ob = out + (size_t)b * 1048576 + y * 64;
    #pragma unroll
    for (int mt = 0; mt < 2; ++mt)
        #pragma unroll
        for (int nt = 0; nt < 4; ++nt) {
            int px = nt * 16 + m;
            #pragma unroll
            for (int r = 0; r < 4; ++r) {
                int oc = w * 32 + mt * 16 + lg * 4 + r;
                ob[(size_t)oc * 4096 + px] = oa[mt][nt][r] + b_out[oc];
            }
        }
}

extern "C" void kernel_launch(void* const* d_in, const int* in_sizes, int n_in,
                              void* d_out, int out_size, void* d_ws, size_t ws_size,
                              hipStream_t stream) {
    const float* x      = (const float*)d_in[0];
    const float* w_proj = (const float*)d_in[1];
    const float* pos    = (const float*)d_in[2];
    const float* w_out  = (const float*)d_in[3];
    const float* b_out  = (const float*)d_in[4];
    float* out = (float*)d_out;

    // d_ws: [0,32M) x_tw ; +32M w16k (384K) ; wo16k (128K) ; Ows (32M)
    u16* xtw   = (u16*)d_ws;
    u16* w16k  = (u16*)((char*)d_ws + 33554432);
    u16* wo16k = (u16*)((char*)d_ws + 33554432 + 393216);
    u16* Ows   = (u16*)((char*)d_ws + 33554432 + 393216 + 131072);

    prep<<<1536, 512, 0, stream>>>(x, w_proj, w_out, xtw, w16k, wo16k);
    lsa_qkv_attn_xt<<<dim3(128, 16), 512, 0, stream>>>(xtw, w16k, pos, Ows);
    lsa_outproj_row<<<dim3(64, 16), 512, 0, stream>>>(Ows, wo16k, b_out, out);
}

// Round 18
// 94.045 us; speedup vs baseline: 2.9257x; 1.1925x over previous
//
#include <hip/hip_runtime.h>

// LocalSelfAttention2d  B=16,C=256,H=W=64,P=8,HEADS=8,D=32
// Round 18: R17's Q-in-registers structure (verified correct, absmax
// 0.03125) with launch_bounds relaxed (512,6)->(512,4). R17's 85-VGPR cap
// spilled the 48-VGPR accumulator footprint (WRITE_SIZE 132MB, VGPR=40);
// at 128-cap: no spills, 2 blocks/CU. Vs R15 keeps: Qb LDS freed (43KB),
// no Q-scatter, no qf LDS reads. prep/K2 unchanged (BW floor).
// MFMA 16x16x32_f16 (verified): A row=l&15, B col=l&15, D col=l&15(B-idx),
// row=(l>>4)*4+r(A-idx); contraction needs only A/B (lg,v)->k agreement.

typedef _Float16 f16x8 __attribute__((ext_vector_type(8)));
typedef _Float16 f16x4v __attribute__((ext_vector_type(4)));
typedef float    f32x4 __attribute__((ext_vector_type(4)));
typedef unsigned short u16;
typedef unsigned int   u32;
typedef unsigned long long u64;

#define SCALE 0.17677669529663687f  // 1/sqrt(32)
#define QK_S  40    // K [64 pix][40 d]
#define VT_S  72    // V [32 d][72 k]
#define LT_S  264   // transpose staging stride
#define XW_S  264   // x-window LDS stride (528B rows, 2-way banks)
#define OT_S  264   // K2 row-tile stride

__device__ __forceinline__ u16 f2hu(float f) {
    _Float16 h = (_Float16)f; return __builtin_bit_cast(u16, h);
}
__device__ __forceinline__ u64 pack4h(f32x4 v) {
    u32 lo = __builtin_bit_cast(u32, __builtin_amdgcn_cvt_pkrtz(v[0], v[1]));
    u32 hi = __builtin_bit_cast(u32, __builtin_amdgcn_cvt_pkrtz(v[2], v[3]));
    return ((u64)hi << 32) | (u64)lo;
}
__device__ __forceinline__ f16x8 cat44(f16x4v a, f16x4v b) {
    return __builtin_shufflevector(a, b, 0, 1, 2, 3, 4, 5, 6, 7);
}

// ---------------- prep: fused weight-convert + x transpose (R13) ----------------
__global__ __launch_bounds__(512)
void prep(const float* __restrict__ x, const float* __restrict__ wp,
          const float* __restrict__ wo, u16* __restrict__ xtw,
          u16* __restrict__ w16k, u16* __restrict__ wo16k)
{
    __shared__ u16 Lt[64 * LT_S];
    const int bid = blockIdx.x;
    const int tid = threadIdx.x;
    if (bid < 1024) {
        const int y = bid & 63, b = bid >> 6;
        const int yq = y >> 3, py = y & 7;
        const float* xb = x + ((size_t)b * 256) * 4096 + y * 64;
        #pragma unroll
        for (int i = 0; i < 8; ++i) {
            int idx = tid + i * 512;            // 4096 float4s
            int c = idx >> 4, w4 = (idx & 15) << 2;
            float4 v = *(const float4*)(xb + (size_t)c * 4096 + w4);
            float vv[4] = {v.x, v.y, v.z, v.w};
            #pragma unroll
            for (int j = 0; j < 4; ++j) {
                int w = w4 + j;
                Lt[w * LT_S + (c ^ (((w >> 2) & 7) << 3))] = f2hu(vv[j]);
            }
        }
        __syncthreads();
        u16* dst = xtw + (size_t)(b * 64 + yq * 8) * 16384;   // window-row base
        #pragma unroll
        for (int i = 0; i < 4; ++i) {
            int idx = tid + i * 512;            // 2048 f16x8 stores
            int w = idx >> 5, c8 = (idx & 31) << 3;
            f16x8 v = *(const f16x8*)(&Lt[w * LT_S + (c8 ^ (((w >> 2) & 7) << 3))]);
            *(f16x8*)(dst + (w >> 3) * 16384 + (py * 8 + (w & 7)) * 256 + c8) = v;
        }
    } else {
        int idx = (bid - 1024) * 512 + tid;     // 0..262143
        if (idx < 196608) {
            int hq = idx / 98304, o = idx - hq * 98304;
            int kt = o / 12288, o2 = o - kt * 12288;
            int lr = o2 >> 5, cc = o2 & 31;
            int s = lr >> 7, hh = (lr >> 5) & 3, d = lr & 31;
            w16k[idx] = f2hu(wp[(size_t)(s * 256 + (hq * 4 + hh) * 32 + d) * 256 + kt * 32 + cc]);
        } else {
            int j = idx - 196608;               // 0..65535
            int kt = j >> 13, o2 = j & 8191;
            int row = o2 >> 5, cc = o2 & 31;
            wo16k[j] = f2hu(wo[(size_t)row * 256 + kt * 32 + cc]);
        }
    }
}

// ---------------- K1: QKV projection + windowed attention ----------------
__global__ __launch_bounds__(512, 4)
void lsa_qkv_attn_xt(const u16* __restrict__ xtw, const u16* __restrict__ w16k,
                     const float* __restrict__ position, u16* __restrict__ Ows)
{
    // U overlay: phase 1-2: XwL[64][264] = 16896 u16 (33792 B)
    //            phase 3-4: Kb [4][64][40] = 10240 | Vt [4][32][72] = 9216
    __shared__ u16 U[19456];        // 38912 B
    __shared__ float POSL[1024];    // 4096 B: this block's hq-half (4 heads)
    u16* XwL = U;                   // [64][264]
    u16* Kb  = U;                   // [4][64][40]
    u16* Vt  = U + 10240;           // [4][32][72]

    const int tid = threadIdx.x;
    const int hq = blockIdx.x & 1, win = blockIdx.x >> 1, b = blockIdx.y;
    const int w = tid >> 6, m = tid & 15, lg = (tid >> 4) & 3;
    const int hh = w >> 1, qh = w & 1;      // wave role (phase 2 AND phase 4)

    // stage position half + x window (shared operands)
    *(float2*)(&POSL[tid * 2]) = *(const float2*)(position + hq * 1024 + tid * 2);
    {
        const u16* xwin = xtw + (size_t)(b * 64 + win) * 16384;
        #pragma unroll
        for (int i = 0; i < 4; ++i) {
            int g = tid + i * 512;              // 2048 16B-chunks
            *(f16x8*)(XwL + (g >> 5) * XW_S + (g & 31) * 8) = *(const f16x8*)(xwin + g * 8);
        }
    }
    __syncthreads();

    // ---- phase 2: QKV GEMM.
    //  Q: wave (hh,qh) computes head hh, d 0..31 (2 M-tiles) x ITS 2 pix-tiles
    //     (qh in the ADDRESS, never an array index - rule #20).
    //  K/V: wave w owns row-tiles 2w, 2w+1 of 16 (K=0..7, V=8..15) x 4 pix-tiles.
    f32x4 accQ[2][2];               // [d-tile t][n]
    f32x4 accKV[2][4];              // [j][nt]
    int lrowKV[2], isvKV[2], hhKV[2], d0KV[2];
    {
        const f32x4 z = {0.f, 0.f, 0.f, 0.f};
        #pragma unroll
        for (int t = 0; t < 2; ++t) { accQ[t][0] = z; accQ[t][1] = z; }
        #pragma unroll
        for (int j = 0; j < 2; ++j) {
            #pragma unroll
            for (int nt = 0; nt < 4; ++nt) accKV[j][nt] = z;
            int t2 = 2 * w + j;                 // 0..15
            isvKV[j] = t2 >> 3;                 // 0=K, 1=V
            hhKV[j] = (t2 >> 1) & 3;
            d0KV[j] = (t2 & 1) * 16;
            lrowKV[j] = (1 + isvKV[j]) * 128 + hhKV[j] * 32 + d0KV[j];  // s=1 K, s=2 V
        }
        const u16* wbase = w16k + (size_t)hq * 98304;
        #pragma unroll
        for (int kt = 0; kt < 8; ++kt) {
            f16x8 afq[2], afkv[2];
            #pragma unroll
            for (int t = 0; t < 2; ++t)        // Q rows: s=0, head hh, d-tile t
                afq[t] = *(const f16x8*)(wbase + kt * 12288 + (hh * 32 + t * 16 + m) * 32 + lg * 8);
            #pragma unroll
            for (int j = 0; j < 2; ++j)
                afkv[j] = *(const f16x8*)(wbase + kt * 12288 + (lrowKV[j] + m) * 32 + lg * 8);
            // K/V: bf loaded one-at-a-time (live range 1, not 4)
            #pragma unroll
            for (int nt = 0; nt < 4; ++nt) {
                f16x8 bf = *(const f16x8*)(XwL + (nt * 16 + m) * XW_S + kt * 32 + lg * 8);
                accKV[0][nt] = __builtin_amdgcn_mfma_f32_16x16x32_f16(afkv[0], bf, accKV[0][nt], 0, 0, 0);
                accKV[1][nt] = __builtin_amdgcn_mfma_f32_16x16x32_f16(afkv[1], bf, accKV[1][nt], 0, 0, 0);
            }
            // Q: re-load this wave's 2 pix-tiles (qh in address only)
            #pragma unroll
            for (int n = 0; n < 2; ++n) {
                f16x8 bq = *(const f16x8*)(XwL + ((2 * qh + n) * 16 + m) * XW_S + kt * 32 + lg * 8);
                accQ[0][n] = __builtin_amdgcn_mfma_f32_16x16x32_f16(afq[0], bq, accQ[0][n], 0, 0, 0);
                accQ[1][n] = __builtin_amdgcn_mfma_f32_16x16x32_f16(afq[1], bq, accQ[1][n], 0, 0, 0);
            }
        }
    }
    __syncthreads();   // XwL reads done before K/V overlay U

    // ---- phase 3: scatter K/V only (Q stays in registers)
    {
        #pragma unroll
        for (int j = 0; j < 2; ++j) {
            int hhj = hhKV[j], d0j = d0KV[j];
            #pragma unroll
            for (int nt = 0; nt < 4; ++nt) {
                int pix = nt * 16 + m;
                if (isvKV[j] == 0) {
                    *(u64*)(Kb + hhj * 64 * QK_S + pix * QK_S + d0j + lg * 4) = pack4h(accKV[j][nt]);
                } else {
                    #pragma unroll
                    for (int r = 0; r < 4; ++r)
                        Vt[hhj * 32 * VT_S + (d0j + lg * 4 + r) * VT_S + pix] = f2hu(accKV[j][nt][r]);
                }
            }
        }
    }
    __syncthreads();

    // ---- phase 4: attention; Q in registers, P in registers
    {
        const u16* Kh = Kb + hh * 64 * QK_S;
        const u16* Vh = Vt + hh * 32 * VT_S;
        const float* posh = &POSL[hh * 256];

        // qf via d-mapping d(lg,v)=(v>>2)*16+lg*4+(v&3): pure in-register
        f16x8 qf[2];
        #pragma unroll
        for (int qi = 0; qi < 2; ++qi) {
            f16x4v q0 = __builtin_bit_cast(f16x4v, pack4h(accQ[0][qi]));
            f16x4v q1 = __builtin_bit_cast(f16x4v, pack4h(accQ[1][qi]));
            qf[qi] = cat44(q0, q1);
        }

        const f32x4 z = {0.f, 0.f, 0.f, 0.f};
        f32x4 st[4][2];
        // kf loaded per-kt (same d-mapping), live range 1
        #pragma unroll
        for (int kt = 0; kt < 4; ++kt) {
            const u16* krow = Kh + (kt * 16 + m) * QK_S + lg * 4;
            f16x8 kf = cat44(*(const f16x4v*)(krow), *(const f16x4v*)(krow + 16));
            st[kt][0] = __builtin_amdgcn_mfma_f32_16x16x32_f16(kf, qf[0], z, 0, 0, 0);
            st[kt][1] = __builtin_amdgcn_mfma_f32_16x16x32_f16(kf, qf[1], z, 0, 0, 0);
        }
        // lane holds S[q=(2qh+qi)*16+m][k=kt*16+lg*4+r]

        float inv[2];
        #pragma unroll
        for (int qi = 0; qi < 2; ++qi) {
            int q = (2 * qh + qi) * 16 + m, qy = q >> 3, qx = q & 7;
            float mx = -1e30f;
            #pragma unroll
            for (int kt = 0; kt < 4; ++kt)
                #pragma unroll
                for (int r = 0; r < 4; ++r) {
                    int k = kt * 16 + lg * 4 + r, ky = k >> 3, kx = k & 7;
                    float t = st[kt][qi][r] * SCALE + posh[(ky - qy + 8) * 16 + (kx - qx + 8)];
                    st[kt][qi][r] = t;
                    mx = fmaxf(mx, t);
                }
            mx = fmaxf(mx, __shfl_xor(mx, 16));
            mx = fmaxf(mx, __shfl_xor(mx, 32));
            float sum = 0.f;
            #pragma unroll
            for (int kt = 0; kt < 4; ++kt)
                #pragma unroll
                for (int r = 0; r < 4; ++r) {
                    float e = __expf(st[kt][qi][r] - mx);
                    st[kt][qi][r] = e; sum += e;
                }
            sum += __shfl_xor(sum, 16);
            sum += __shfl_xor(sum, 32);
            inv[qi] = 1.f / sum;
        }

        // PV with k-mapping k(lg,v) = (2ks+(v>>2))*16 + lg*4 + (v&3) (R15-verified)
        f32x4 ot[2][2];
        ot[0][0] = z; ot[0][1] = z; ot[1][0] = z; ot[1][1] = z;
        #pragma unroll
        for (int ks = 0; ks < 2; ++ks) {
            f16x8 pf[2], vf[2];
            #pragma unroll
            for (int qi = 0; qi < 2; ++qi) {
                f16x4v lo = __builtin_bit_cast(f16x4v, pack4h(st[2 * ks + 0][qi] * inv[qi]));
                f16x4v hi = __builtin_bit_cast(f16x4v, pack4h(st[2 * ks + 1][qi] * inv[qi]));
                pf[qi] = cat44(lo, hi);
            }
            #pragma unroll
            for (int dt = 0; dt < 2; ++dt) {
                const u16* vrow = Vh + (dt * 16 + m) * VT_S + lg * 4;
                f16x4v v0 = *(const f16x4v*)(vrow + (2 * ks + 0) * 16);
                f16x4v v1 = *(const f16x4v*)(vrow + (2 * ks + 1) * 16);
                vf[dt] = cat44(v0, v1);
            }
            #pragma unroll
            for (int qi = 0; qi < 2; ++qi)
                #pragma unroll
                for (int dt = 0; dt < 2; ++dt)
                    ot[qi][dt] = __builtin_amdgcn_mfma_f32_16x16x32_f16(pf[qi], vf[dt], ot[qi][dt], 0, 0, 0);
        }

        // O -> Ows [bw][pix][c] fp16 (lane=c-col, regs=q-rows)
        const size_t obase = (size_t)(b * 64 + win) * 16384;
        const int head = hq * 4 + hh;
        #pragma unroll
        for (int qi = 0; qi < 2; ++qi)
            #pragma unroll
            for (int dt = 0; dt < 2; ++dt) {
                int c = head * 32 + dt * 16 + m;
                #pragma unroll
                for (int r = 0; r < 4; ++r) {
                    int q = (2 * qh + qi) * 16 + lg * 4 + r;
                    Ows[obase + q * 256 + c] = f2hu(ot[qi][dt][r]);
                }
            }
    }
}

// -------- K2: out-projection, ROW-major blocks (unchanged R13) --------
__global__ __launch_bounds__(512, 4)
void lsa_outproj_row(const u16* __restrict__ Ows, const u16* __restrict__ wo16k,
                     const float* __restrict__ b_out, float* __restrict__ out)
{
    __shared__ u16 Ot[64 * OT_S];    // 33792 B [64 px][264 c]

    const int tid = threadIdx.x;
    const int y = blockIdx.x, b = blockIdx.y;
    const int yq = y >> 3, py = y & 7;
    const int w = tid >> 6, m = tid & 15, lg = (tid >> 4) & 3;

    {
        const u16* slab = Ows + (size_t)(b * 64 + yq * 8) * 16384 + (py * 8) * 256;
        #pragma unroll
        for (int i = 0; i < 4; ++i) {
            int g = tid + i * 512;              // 2048 16B-chunks
            int wx = g >> 8, gg = g & 255;
            int lx = gg >> 5, c8 = (gg & 31) << 3;
            f16x8 v = *(const f16x8*)(slab + (size_t)wx * 16384 + lx * 256 + c8);
            *(f16x8*)(Ot + (wx * 8 + lx) * OT_S + c8) = v;
        }
    }
    __syncthreads();

    f32x4 oa[2][4];
    {
        const f32x4 z = {0.f, 0.f, 0.f, 0.f};
        #pragma unroll
        for (int mt = 0; mt < 2; ++mt)
            #pragma unroll
            for (int nt = 0; nt < 4; ++nt) oa[mt][nt] = z;
    }
    #pragma unroll
    for (int kt = 0; kt < 8; ++kt) {
        f16x8 wf[2], of[4];
        #pragma unroll
        for (int mt = 0; mt < 2; ++mt)
            wf[mt] = *(const f16x8*)(wo16k + kt * 8192 + (w * 32 + mt * 16 + m) * 32 + lg * 8);
        #pragma unroll
        for (int nt = 0; nt < 4; ++nt)
            of[nt] = *(const f16x8*)(Ot + (nt * 16 + m) * OT_S + kt * 32 + lg * 8);
        #pragma unroll
        for (int mt = 0; mt < 2; ++mt)
            #pragma unroll
            for (int nt = 0; nt < 4; ++nt)
                oa[mt][nt] = __builtin_amdgcn_mfma_f32_16x16x32_f16(wf[mt], of[nt], oa[mt][nt], 0, 0, 0);
    }
    // write out[b][oc][y][px]: 16 consecutive px per (oc) -> 64B segments
    float* ob = out + (size_t)b * 1048576 + y * 64;
    #pragma unroll
    for (int mt = 0; mt < 2; ++mt)
        #pragma unroll
        for (int nt = 0; nt < 4; ++nt) {
            int px = nt * 16 + m;
            #pragma unroll
            for (int r = 0; r < 4; ++r) {
                int oc = w * 32 + mt * 16 + lg * 4 + r;
                ob[(size_t)oc * 4096 + px] = oa[mt][nt][r] + b_out[oc];
            }
        }
}

extern "C" void kernel_launch(void* const* d_in, const int* in_sizes, int n_in,
                              void* d_out, int out_size, void* d_ws, size_t ws_size,
                              hipStream_t stream) {
    const float* x      = (const float*)d_in[0];
    const float* w_proj = (const float*)d_in[1];
    const float* pos    = (const float*)d_in[2];
    const float* w_out  = (const float*)d_in[3];
    const float* b_out  = (const float*)d_in[4];
    float* out = (float*)d_out;

    // d_ws: [0,32M) x_tw ; +32M w16k (384K) ; wo16k (128K) ; Ows (32M)
    u16* xtw   = (u16*)d_ws;
    u16* w16k  = (u16*)((char*)d_ws + 33554432);
    u16* wo16k = (u16*)((char*)d_ws + 33554432 + 393216);
    u16* Ows   = (u16*)((char*)d_ws + 33554432 + 393216 + 131072);

    prep<<<1536, 512, 0, stream>>>(x, w_proj, w_out, xtw, w16k, wo16k);
    lsa_qkv_attn_xt<<<dim3(128, 16), 512, 0, stream>>>(xtw, w16k, pos, Ows);
    lsa_outproj_row<<<dim3(64, 16), 512, 0, stream>>>(Ows, wo16k, b_out, out);
}

// Round 19
// 91.734 us; speedup vs baseline: 2.9994x; 1.0252x over previous
//
#include <hip/hip_runtime.h>

// LocalSelfAttention2d  B=16,C=256,H=W=64,P=8,HEADS=8,D=32
// Round 19: R15 structure (best: 88.6us; Q in LDS, P in registers) split into
// 256-thread blocks, one per HEAD-PAIR (grid 4096 = win x b x quadrant).
// Total staging chunks / MFMAs / per-wave work IDENTICAL to R15; LDS per
// block 35.8KB -> 4 blocks/CU -> 4 independent barrier domains per CU
// (was 2) for latency hiding. prep/K2 unchanged (BW floor).
// MFMA 16x16x32_f16 (verified): A row=l&15, B col=l&15, D col=l&15(B-idx),
// row=(l>>4)*4+r(A-idx); PV k-mapping k(lg,v)=(2ks+(v>>2))*16+lg*4+(v&3).

typedef _Float16 f16x8 __attribute__((ext_vector_type(8)));
typedef _Float16 f16x4v __attribute__((ext_vector_type(4)));
typedef float    f32x4 __attribute__((ext_vector_type(4)));
typedef unsigned short u16;
typedef unsigned int   u32;
typedef unsigned long long u64;

#define SCALE 0.17677669529663687f  // 1/sqrt(32)
#define QK_S  40    // Q/K [64 pix][40 d]
#define VT_S  72    // V [32 d][72 k]
#define LT_S  264   // transpose staging stride
#define XW_S  264   // x-window LDS stride (528B rows, 2-way banks)
#define OT_S  264   // K2 row-tile stride

__device__ __forceinline__ u16 f2hu(float f) {
    _Float16 h = (_Float16)f; return __builtin_bit_cast(u16, h);
}
__device__ __forceinline__ u64 pack4h(f32x4 v) {
    u32 lo = __builtin_bit_cast(u32, __builtin_amdgcn_cvt_pkrtz(v[0], v[1]));
    u32 hi = __builtin_bit_cast(u32, __builtin_amdgcn_cvt_pkrtz(v[2], v[3]));
    return ((u64)hi << 32) | (u64)lo;
}
__device__ __forceinline__ f16x8 cat44(f16x4v a, f16x4v b) {
    return __builtin_shufflevector(a, b, 0, 1, 2, 3, 4, 5, 6, 7);
}

// ---------------- prep: fused weight-convert + x transpose (R13) ----------------
__global__ __launch_bounds__(512)
void prep(const float* __restrict__ x, const float* __restrict__ wp,
          const float* __restrict__ wo, u16* __restrict__ xtw,
          u16* __restrict__ w16k, u16* __restrict__ wo16k)
{
    __shared__ u16 Lt[64 * LT_S];
    const int bid = blockIdx.x;
    const int tid = threadIdx.x;
    if (bid < 1024) {
        const int y = bid & 63, b = bid >> 6;
        const int yq = y >> 3, py = y & 7;
        const float* xb = x + ((size_t)b * 256) * 4096 + y * 64;
        #pragma unroll
        for (int i = 0; i < 8; ++i) {
            int idx = tid + i * 512;            // 4096 float4s
            int c = idx >> 4, w4 = (idx & 15) << 2;
            float4 v = *(const float4*)(xb + (size_t)c * 4096 + w4);
            float vv[4] = {v.x, v.y, v.z, v.w};
            #pragma unroll
            for (int j = 0; j < 4; ++j) {
                int w = w4 + j;
                Lt[w * LT_S + (c ^ (((w >> 2) & 7) << 3))] = f2hu(vv[j]);
            }
        }
        __syncthreads();
        u16* dst = xtw + (size_t)(b * 64 + yq * 8) * 16384;   // window-row base
        #pragma unroll
        for (int i = 0; i < 4; ++i) {
            int idx = tid + i * 512;            // 2048 f16x8 stores
            int w = idx >> 5, c8 = (idx & 31) << 3;
            f16x8 v = *(const f16x8*)(&Lt[w * LT_S + (c8 ^ (((w >> 2) & 7) << 3))]);
            *(f16x8*)(dst + (w >> 3) * 16384 + (py * 8 + (w & 7)) * 256 + c8) = v;
        }
    } else {
        int idx = (bid - 1024) * 512 + tid;     // 0..262143
        if (idx < 196608) {
            int hq = idx / 98304, o = idx - hq * 98304;
            int kt = o / 12288, o2 = o - kt * 12288;
            int lr = o2 >> 5, cc = o2 & 31;
            int s = lr >> 7, hh = (lr >> 5) & 3, d = lr & 31;
            w16k[idx] = f2hu(wp[(size_t)(s * 256 + (hq * 4 + hh) * 32 + d) * 256 + kt * 32 + cc]);
        } else {
            int j = idx - 196608;               // 0..65535
            int kt = j >> 13, o2 = j & 8191;
            int row = o2 >> 5, cc = o2 & 31;
            wo16k[j] = f2hu(wo[(size_t)row * 256 + kt * 32 + cc]);
        }
    }
}

// ---------------- K1: QKV projection + windowed attention (256-thr blocks) ----------------
__global__ __launch_bounds__(256, 4)
void lsa_qkv_attn_xt(const u16* __restrict__ xtw, const u16* __restrict__ w16k,
                     const float* __restrict__ position, u16* __restrict__ Ows)
{
    // Block = (win, b, quadrant q2): heads q2*2 .. q2*2+1. 4 waves.
    // U overlay: phase 1-2: XwL[64][264] = 16896 u16 (33792 B)
    //            phase 3-4: Qb 5120 | Kb 5120 | Vt 4608 (14848 u16)
    __shared__ u16 U[16896];        // 33792 B
    __shared__ float POSL[512];     // 2048 B: this block's 2 heads
    u16* XwL = U;                   // [64][264]
    u16* Qb  = U;                   // [2][64][40]
    u16* Kb  = U + 5120;            // [2][64][40]
    u16* Vt  = U + 10240;           // [2][32][72]

    const int tid = threadIdx.x;
    const int q2 = blockIdx.x & 3, win = blockIdx.x >> 2, b = blockIdx.y;
    const int hq = q2 >> 1, hp = q2 & 1;    // 4-head group, pair within group
    const int w = tid >> 6, m = tid & 15, lg = (tid >> 4) & 3;
    const int hh = w >> 1, qh = w & 1;      // local head (0..1), q-half

    // stage position pair + x window (shared operands)
    *(float2*)(&POSL[tid * 2]) = *(const float2*)(position + q2 * 512 + tid * 2);
    {
        const u16* xwin = xtw + (size_t)(b * 64 + win) * 16384;
        #pragma unroll
        for (int i = 0; i < 8; ++i) {
            int g = tid + i * 256;              // 2048 16B-chunks
            *(f16x8*)(XwL + (g >> 5) * XW_S + (g & 31) * 8) = *(const f16x8*)(xwin + g * 8);
        }
    }
    __syncthreads();

    // ---- phase 2: QKV GEMM; A (weights) direct global, B (window) from LDS.
    //  192 local rows = s*64 + hhl*32 + d (s: 0=Q,1=K,2=V; hhl: local head).
    //  Wave w owns row-tiles 3w..3w+2 (12 tiles / 4 waves).
    f32x4 acc[3][4];
    int isv[3], hhv[3], d0v[3], grow[3];
    {
        const f32x4 z = {0.f, 0.f, 0.f, 0.f};
        #pragma unroll
        for (int i = 0; i < 3; ++i) {
            #pragma unroll
            for (int nt = 0; nt < 4; ++nt) acc[i][nt] = z;
            int lr0 = (3 * w + i) * 16;           // 0..176
            isv[i] = lr0 >> 6;                    // 0=Q,1=K,2=V
            int rem = lr0 & 63;
            hhv[i] = rem >> 5;                    // local head 0..1
            d0v[i] = rem & 31;                    // 0 or 16
            grow[i] = isv[i] * 128 + (hp * 2 + hhv[i]) * 32 + d0v[i];  // w16k row
        }
        const u16* wbase = w16k + (size_t)hq * 98304;
        #pragma unroll
        for (int kt = 0; kt < 8; ++kt) {
            f16x8 af[3], bf[4];
            #pragma unroll
            for (int i = 0; i < 3; ++i)
                af[i] = *(const f16x8*)(wbase + kt * 12288 + (grow[i] + m) * 32 + lg * 8);
            #pragma unroll
            for (int nt = 0; nt < 4; ++nt)
                bf[nt] = *(const f16x8*)(XwL + (nt * 16 + m) * XW_S + kt * 32 + lg * 8);
            #pragma unroll
            for (int i = 0; i < 3; ++i)
                #pragma unroll
                for (int nt = 0; nt < 4; ++nt)
                    acc[i][nt] = __builtin_amdgcn_mfma_f32_16x16x32_f16(af[i], bf[nt], acc[i][nt], 0, 0, 0);
        }
    }
    __syncthreads();   // XwL reads done before Q/K/V overlay U

    // ---- phase 3: scatter Q/K/V to per-head LDS
    {
        #pragma unroll
        for (int i = 0; i < 3; ++i) {
            int i_s = isv[i], hhl = hhv[i], d0 = d0v[i];
            #pragma unroll
            for (int nt = 0; nt < 4; ++nt) {
                int pix = nt * 16 + m;
                if (i_s < 2) {
                    u16* base = (i_s == 0) ? Qb : Kb;
                    *(u64*)(base + hhl * 64 * QK_S + pix * QK_S + d0 + lg * 4) = pack4h(acc[i][nt]);
                } else {
                    #pragma unroll
                    for (int r = 0; r < 4; ++r)
                        Vt[hhl * 32 * VT_S + (d0 + lg * 4 + r) * VT_S + pix] = f2hu(acc[i][nt][r]);
                }
            }
        }
    }
    __syncthreads();

    // ---- phase 4: attention; wave = (hh, qh); P fully in registers (R15)
    {
        const u16* Qh = Qb + hh * 64 * QK_S;
        const u16* Kh = Kb + hh * 64 * QK_S;
        const u16* Vh = Vt + hh * 32 * VT_S;
        const float* posh = &POSL[hh * 256];

        f16x8 kf[4], qf[2];
        #pragma unroll
        for (int kt = 0; kt < 4; ++kt)
            kf[kt] = *(const f16x8*)(Kh + (kt * 16 + m) * QK_S + lg * 8);
        #pragma unroll
        for (int qi = 0; qi < 2; ++qi)
            qf[qi] = *(const f16x8*)(Qh + ((2 * qh + qi) * 16 + m) * QK_S + lg * 8);
        // no barrier needed: phase 4 performs no LDS writes

        const f32x4 z = {0.f, 0.f, 0.f, 0.f};
        f32x4 st[4][2];
        #pragma unroll
        for (int kt = 0; kt < 4; ++kt)
            #pragma unroll
            for (int qi = 0; qi < 2; ++qi)
                st[kt][qi] = __builtin_amdgcn_mfma_f32_16x16x32_f16(kf[kt], qf[qi], z, 0, 0, 0);
        // lane holds S[q=(2qh+qi)*16+m][k=kt*16+lg*4+r]

        float inv[2];
        #pragma unroll
        for (int qi = 0; qi < 2; ++qi) {
            int q = (2 * qh + qi) * 16 + m, qy = q >> 3, qx = q & 7;
            float mx = -1e30f;
            #pragma unroll
            for (int kt = 0; kt < 4; ++kt)
                #pragma unroll
                for (int r = 0; r < 4; ++r) {
                    int k = kt * 16 + lg * 4 + r, ky = k >> 3, kx = k & 7;
                    float t = st[kt][qi][r] * SCALE + posh[(ky - qy + 8) * 16 + (kx - qx + 8)];
                    st[kt][qi][r] = t;
                    mx = fmaxf(mx, t);
                }
            mx = fmaxf(mx, __shfl_xor(mx, 16));
            mx = fmaxf(mx, __shfl_xor(mx, 32));
            float sum = 0.f;
            #pragma unroll
            for (int kt = 0; kt < 4; ++kt)
                #pragma unroll
                for (int r = 0; r < 4; ++r) {
                    float e = __expf(st[kt][qi][r] - mx);
                    st[kt][qi][r] = e; sum += e;
                }
            sum += __shfl_xor(sum, 16);
            sum += __shfl_xor(sum, 32);
            inv[qi] = 1.f / sum;
        }

        // PV with k-mapping k(lg,v) = (2ks+(v>>2))*16 + lg*4 + (v&3) (R15-verified)
        f32x4 ot[2][2];
        ot[0][0] = z; ot[0][1] = z; ot[1][0] = z; ot[1][1] = z;
        #pragma unroll
        for (int ks = 0; ks < 2; ++ks) {
            f16x8 pf[2], vf[2];
            #pragma unroll
            for (int qi = 0; qi < 2; ++qi) {
                f16x4v lo = __builtin_bit_cast(f16x4v, pack4h(st[2 * ks + 0][qi] * inv[qi]));
                f16x4v hi = __builtin_bit_cast(f16x4v, pack4h(st[2 * ks + 1][qi] * inv[qi]));
                pf[qi] = cat44(lo, hi);
            }
            #pragma unroll
            for (int dt = 0; dt < 2; ++dt) {
                const u16* vrow = Vh + (dt * 16 + m) * VT_S + lg * 4;
                f16x4v v0 = *(const f16x4v*)(vrow + (2 * ks + 0) * 16);
                f16x4v v1 = *(const f16x4v*)(vrow + (2 * ks + 1) * 16);
                vf[dt] = cat44(v0, v1);
            }
            #pragma unroll
            for (int qi = 0; qi < 2; ++qi)
                #pragma unroll
                for (int dt = 0; dt < 2; ++dt)
                    ot[qi][dt] = __builtin_amdgcn_mfma_f32_16x16x32_f16(pf[qi], vf[dt], ot[qi][dt], 0, 0, 0);
        }

        // O -> Ows [bw][pix][c] fp16 (lane=c-col, regs=q-rows)
        const size_t obase = (size_t)(b * 64 + win) * 16384;
        const int head = q2 * 2 + hh;
        #pragma unroll
        for (int qi = 0; qi < 2; ++qi)
            #pragma unroll
            for (int dt = 0; dt < 2; ++dt) {
                int c = head * 32 + dt * 16 + m;
                #pragma unroll
                for (int r = 0; r < 4; ++r) {
                    int q = (2 * qh + qi) * 16 + lg * 4 + r;
                    Ows[obase + q * 256 + c] = f2hu(ot[qi][dt][r]);
                }
            }
    }
}

// -------- K2: out-projection, ROW-major blocks (unchanged R13) --------
__global__ __launch_bounds__(512, 4)
void lsa_outproj_row(const u16* __restrict__ Ows, const u16* __restrict__ wo16k,
                     const float* __restrict__ b_out, float* __restrict__ out)
{
    __shared__ u16 Ot[64 * OT_S];    // 33792 B [64 px][264 c]

    const int tid = threadIdx.x;
    const int y = blockIdx.x, b = blockIdx.y;
    const int yq = y >> 3, py = y & 7;
    const int w = tid >> 6, m = tid & 15, lg = (tid >> 4) & 3;

    {
        const u16* slab = Ows + (size_t)(b * 64 + yq * 8) * 16384 + (py * 8) * 256;
        #pragma unroll
        for (int i = 0; i < 4; ++i) {
            int g = tid + i * 512;              // 2048 16B-chunks
            int wx = g >> 8, gg = g & 255;
            int lx = gg >> 5, c8 = (gg & 31) << 3;
            f16x8 v = *(const f16x8*)(slab + (size_t)wx * 16384 + lx * 256 + c8);
            *(f16x8*)(Ot + (wx * 8 + lx) * OT_S + c8) = v;
        }
    }
    __syncthreads();

    f32x4 oa[2][4];
    {
        const f32x4 z = {0.f, 0.f, 0.f, 0.f};
        #pragma unroll
        for (int mt = 0; mt < 2; ++mt)
            #pragma unroll
            for (int nt = 0; nt < 4; ++nt) oa[mt][nt] = z;
    }
    #pragma unroll
    for (int kt = 0; kt < 8; ++kt) {
        f16x8 wf[2], of[4];
        #pragma unroll
        for (int mt = 0; mt < 2; ++mt)
            wf[mt] = *(const f16x8*)(wo16k + kt * 8192 + (w * 32 + mt * 16 + m) * 32 + lg * 8);
        #pragma unroll
        for (int nt = 0; nt < 4; ++nt)
            of[nt] = *(const f16x8*)(Ot + (nt * 16 + m) * OT_S + kt * 32 + lg * 8);
        #pragma unroll
        for (int mt = 0; mt < 2; ++mt)
            #pragma unroll
            for (int nt = 0; nt < 4; ++nt)
                oa[mt][nt] = __builtin_amdgcn_mfma_f32_16x16x32_f16(wf[mt], of[nt], oa[mt][nt], 0, 0, 0);
    }
    // write out[b][oc][y][px]: 16 consecutive px per (oc) -> 64B segments
    float* ob = out + (size_t)b * 1048576 + y * 64;
    #pragma unroll
    for (int mt = 0; mt < 2; ++mt)
        #pragma unroll
        for (int nt = 0; nt < 4; ++nt) {
            int px = nt * 16 + m;
            #pragma unroll
            for (int r = 0; r < 4; ++r) {
                int oc = w * 32 + mt * 16 + lg * 4 + r;
                ob[(size_t)oc * 4096 + px] = oa[mt][nt][r] + b_out[oc];
            }
        }
}

extern "C" void kernel_launch(void* const* d_in, const int* in_sizes, int n_in,
                              void* d_out, int out_size, void* d_ws, size_t ws_size,
                              hipStream_t stream) {
    const float* x      = (const float*)d_in[0];
    const float* w_proj = (const float*)d_in[1];
    const float* pos    = (const float*)d_in[2];
    const float* w_out  = (const float*)d_in[3];
    const float* b_out  = (const float*)d_in[4];
    float* out = (float*)d_out;

    // d_ws: [0,32M) x_tw ; +32M w16k (384K) ; wo16k (128K) ; Ows (32M)
    u16* xtw   = (u16*)d_ws;
    u16* w16k  = (u16*)((char*)d_ws + 33554432);
    u16* wo16k = (u16*)((char*)d_ws + 33554432 + 393216);
    u16* Ows   = (u16*)((char*)d_ws + 33554432 + 393216 + 131072);

    prep<<<1536, 512, 0, stream>>>(x, w_proj, w_out, xtw, w16k, wo16k);
    lsa_qkv_attn_xt<<<dim3(256, 16), 256, 0, stream>>>(xtw, w16k, pos, Ows);
    lsa_outproj_row<<<dim3(64, 16), 512, 0, stream>>>(Ows, wo16k, b_out, out);
}

// Round 20
// 89.089 us; speedup vs baseline: 3.0885x; 1.0297x over previous
//
#include <hip/hip_runtime.h>

// LocalSelfAttention2d  B=16,C=256,H=W=64,P=8,HEADS=8,D=32
// FINAL (= R15, best verified: 88.6us total; 7.8x over fp32 baseline).
// R16-R19 occupancy/LDS arc all null-or-worse -> reverted to this.
// Structure:
//  prep: fused weight fp16 convert (k-chunk-major: w16k[hq][kt][384][32],
//        wo16k[kt][256][32]) + x transpose -> x_tw[b][win][pix][c] fp16.
//  K1 (per win,b,hq-half): stage x-window LDS once (shared operand);
//      QKV GEMM with A=weights DIRECT global (per-wave-contiguous 1KB frag
//      loads); Q/K/V scatter to LDS; attention with P entirely in registers
//      via custom PV k-mapping k(lg,v)=(2ks+(v>>2))*16+lg*4+(v&3).
//  K2 (per image-row): out-proj GEMM, Ows staged (shared), weights direct,
//      output writes in 64B segments.
// Key lessons encoded: LDS-stage SHARED operands once; per-wave-DISTINCT
// operands direct from global in k-chunk-major layout (R8 vs R9 vs R11);
// per-wave-contiguous access beats everything else (TA fragmentation);
// static register indexing only (rule #20, R16 spill).
// MFMA 16x16x32_f16 (verified): A row=l&15, B col=l&15, D col=l&15(B-idx),
// row=(l>>4)*4+r(A-idx); contraction needs only A/B (lg,v)->k agreement.

typedef _Float16 f16x8 __attribute__((ext_vector_type(8)));
typedef _Float16 f16x4v __attribute__((ext_vector_type(4)));
typedef float    f32x4 __attribute__((ext_vector_type(4)));
typedef unsigned short u16;
typedef unsigned int   u32;
typedef unsigned long long u64;

#define SCALE 0.17677669529663687f  // 1/sqrt(32)
#define QK_S  40    // Q/K [64 pix][40 d]
#define VT_S  72    // V [32 d][72 k]
#define LT_S  264   // transpose staging stride
#define XW_S  264   // x-window LDS stride (528B rows, 2-way banks)
#define OT_S  264   // K2 row-tile stride

__device__ __forceinline__ u16 f2hu(float f) {
    _Float16 h = (_Float16)f; return __builtin_bit_cast(u16, h);
}
__device__ __forceinline__ u64 pack4h(f32x4 v) {
    u32 lo = __builtin_bit_cast(u32, __builtin_amdgcn_cvt_pkrtz(v[0], v[1]));
    u32 hi = __builtin_bit_cast(u32, __builtin_amdgcn_cvt_pkrtz(v[2], v[3]));
    return ((u64)hi << 32) | (u64)lo;
}
__device__ __forceinline__ f16x8 cat44(f16x4v a, f16x4v b) {
    return __builtin_shufflevector(a, b, 0, 1, 2, 3, 4, 5, 6, 7);
}

// ---------------- prep: fused weight-convert + x transpose ----------------
__global__ __launch_bounds__(512)
void prep(const float* __restrict__ x, const float* __restrict__ wp,
          const float* __restrict__ wo, u16* __restrict__ xtw,
          u16* __restrict__ w16k, u16* __restrict__ wo16k)
{
    __shared__ u16 Lt[64 * LT_S];
    const int bid = blockIdx.x;
    const int tid = threadIdx.x;
    if (bid < 1024) {
        const int y = bid & 63, b = bid >> 6;
        const int yq = y >> 3, py = y & 7;
        const float* xb = x + ((size_t)b * 256) * 4096 + y * 64;
        #pragma unroll
        for (int i = 0; i < 8; ++i) {
            int idx = tid + i * 512;            // 4096 float4s
            int c = idx >> 4, w4 = (idx & 15) << 2;
            float4 v = *(const float4*)(xb + (size_t)c * 4096 + w4);
            float vv[4] = {v.x, v.y, v.z, v.w};
            #pragma unroll
            for (int j = 0; j < 4; ++j) {
                int w = w4 + j;
                Lt[w * LT_S + (c ^ (((w >> 2) & 7) << 3))] = f2hu(vv[j]);
            }
        }
        __syncthreads();
        u16* dst = xtw + (size_t)(b * 64 + yq * 8) * 16384;   // window-row base
        #pragma unroll
        for (int i = 0; i < 4; ++i) {
            int idx = tid + i * 512;            // 2048 f16x8 stores
            int w = idx >> 5, c8 = (idx & 31) << 3;
            f16x8 v = *(const f16x8*)(&Lt[w * LT_S + (c8 ^ (((w >> 2) & 7) << 3))]);
            *(f16x8*)(dst + (w >> 3) * 16384 + (py * 8 + (w & 7)) * 256 + c8) = v;
        }
    } else {
        int idx = (bid - 1024) * 512 + tid;     // 0..262143
        if (idx < 196608) {
            int hq = idx / 98304, o = idx - hq * 98304;
            int kt = o / 12288, o2 = o - kt * 12288;
            int lr = o2 >> 5, cc = o2 & 31;
            int s = lr >> 7, hh = (lr >> 5) & 3, d = lr & 31;
            w16k[idx] = f2hu(wp[(size_t)(s * 256 + (hq * 4 + hh) * 32 + d) * 256 + kt * 32 + cc]);
        } else {
            int j = idx - 196608;               // 0..65535
            int kt = j >> 13, o2 = j & 8191;
            int row = o2 >> 5, cc = o2 & 31;
            wo16k[j] = f2hu(wo[(size_t)row * 256 + kt * 32 + cc]);
        }
    }
}

// ---------------- K1: QKV projection + windowed attention ----------------
__global__ __launch_bounds__(512, 4)
void lsa_qkv_attn_xt(const u16* __restrict__ xtw, const u16* __restrict__ w16k,
                     const float* __restrict__ position, u16* __restrict__ Ows)
{
    // U overlay: phase 1-2: XwL[64][264] = 16896 u16
    //            phase 3-4: Qb 10240 | Kb 10240 | Vt 9216 = 29696 u16
    __shared__ u16 U[29696];        // 59392 B
    __shared__ float POSL[1024];    // 4096 B: this block's hq-half (4 heads)
    u16* XwL = U;                   // [64][264]
    u16* Qb  = U;                   // [4][64][40]
    u16* Kb  = U + 10240;
    u16* Vt  = U + 20480;           // [4][32][72]

    const int tid = threadIdx.x;
    const int hq = blockIdx.x & 1, win = blockIdx.x >> 1, b = blockIdx.y;
    const int w = tid >> 6, m = tid & 15, lg = (tid >> 4) & 3;

    // stage position half + x window (shared operands)
    *(float2*)(&POSL[tid * 2]) = *(const float2*)(position + hq * 1024 + tid * 2);
    {
        const u16* xwin = xtw + (size_t)(b * 64 + win) * 16384;
        #pragma unroll
        for (int i = 0; i < 4; ++i) {
            int g = tid + i * 512;              // 2048 16B-chunks
            *(f16x8*)(XwL + (g >> 5) * XW_S + (g & 31) * 8) = *(const f16x8*)(xwin + g * 8);
        }
    }
    __syncthreads();

    // ---- phase 2: QKV GEMM; A (weights) direct global, B (window) from LDS
    f32x4 acc[3][4];
    int isv[3], hhv[3], d0v[3], lr0v[3];
    {
        const f32x4 z = {0.f, 0.f, 0.f, 0.f};
        #pragma unroll
        for (int i = 0; i < 3; ++i) {
            #pragma unroll
            for (int nt = 0; nt < 4; ++nt) acc[i][nt] = z;
            int lr0 = (3 * w + i) * 16;           // local row: s*128 + hh*32 + d
            lr0v[i] = lr0;
            isv[i] = lr0 >> 7; hhv[i] = (lr0 >> 5) & 3; d0v[i] = lr0 & 31;
        }
        const u16* wbase = w16k + (size_t)hq * 98304;
        #pragma unroll
        for (int kt = 0; kt < 8; ++kt) {
            f16x8 af[3], bf[4];
            #pragma unroll
            for (int i = 0; i < 3; ++i)
                af[i] = *(const f16x8*)(wbase + kt * 12288 + (lr0v[i] + m) * 32 + lg * 8);
            #pragma unroll
            for (int nt = 0; nt < 4; ++nt)
                bf[nt] = *(const f16x8*)(XwL + (nt * 16 + m) * XW_S + kt * 32 + lg * 8);
            #pragma unroll
            for (int i = 0; i < 3; ++i)
                #pragma unroll
                for (int nt = 0; nt < 4; ++nt)
                    acc[i][nt] = __builtin_amdgcn_mfma_f32_16x16x32_f16(af[i], bf[nt], acc[i][nt], 0, 0, 0);
        }
    }
    __syncthreads();   // XwL reads done before Q/K/V overlay U

    // ---- phase 3: scatter Q/K/V to per-head LDS
    {
        #pragma unroll
        for (int i = 0; i < 3; ++i) {
            int i_s = isv[i], hh = hhv[i], d0 = d0v[i];
            #pragma unroll
            for (int nt = 0; nt < 4; ++nt) {
                int pix = nt * 16 + m;
                if (i_s < 2) {
                    u16* base = (i_s == 0) ? Qb : Kb;
                    *(u64*)(base + hh * 64 * QK_S + pix * QK_S + d0 + lg * 4) = pack4h(acc[i][nt]);
                } else {
                    #pragma unroll
                    for (int r = 0; r < 4; ++r)
                        Vt[hh * 32 * VT_S + (d0 + lg * 4 + r) * VT_S + pix] = f2hu(acc[i][nt][r]);
                }
            }
        }
    }
    __syncthreads();

    // ---- phase 4: attention; 2 waves per head; P fully in registers
    {
        const int hh = w >> 1, qh = w & 1;
        const u16* Qh = Qb + hh * 64 * QK_S;
        const u16* Kh = Kb + hh * 64 * QK_S;
        const u16* Vh = Vt + hh * 32 * VT_S;
        const float* posh = &POSL[hh * 256];

        f16x8 kf[4], qf[2];
        #pragma unroll
        for (int kt = 0; kt < 4; ++kt)
            kf[kt] = *(const f16x8*)(Kh + (kt * 16 + m) * QK_S + lg * 8);
        #pragma unroll
        for (int qi = 0; qi < 2; ++qi)
            qf[qi] = *(const f16x8*)(Qh + ((2 * qh + qi) * 16 + m) * QK_S + lg * 8);
        // no barrier needed: phase 4 performs no LDS writes

        const f32x4 z = {0.f, 0.f, 0.f, 0.f};
        f32x4 st[4][2];
        #pragma unroll
        for (int kt = 0; kt < 4; ++kt)
            #pragma unroll
            for (int qi = 0; qi < 2; ++qi)
                st[kt][qi] = __builtin_amdgcn_mfma_f32_16x16x32_f16(kf[kt], qf[qi], z, 0, 0, 0);
        // lane holds S[q=(2qh+qi)*16+m][k=kt*16+lg*4+r]

        float inv[2];
        #pragma unroll
        for (int qi = 0; qi < 2; ++qi) {
            int q = (2 * qh + qi) * 16 + m, qy = q >> 3, qx = q & 7;
            float mx = -1e30f;
            #pragma unroll
            for (int kt = 0; kt < 4; ++kt)
                #pragma unroll
                for (int r = 0; r < 4; ++r) {
                    int k = kt * 16 + lg * 4 + r, ky = k >> 3, kx = k & 7;
                    float t = st[kt][qi][r] * SCALE + posh[(ky - qy + 8) * 16 + (kx - qx + 8)];
                    st[kt][qi][r] = t;
                    mx = fmaxf(mx, t);
                }
            mx = fmaxf(mx, __shfl_xor(mx, 16));
            mx = fmaxf(mx, __shfl_xor(mx, 32));
            float sum = 0.f;
            #pragma unroll
            for (int kt = 0; kt < 4; ++kt)
                #pragma unroll
                for (int r = 0; r < 4; ++r) {
                    float e = __expf(st[kt][qi][r] - mx);
                    st[kt][qi][r] = e; sum += e;
                }
            sum += __shfl_xor(sum, 16);
            sum += __shfl_xor(sum, 32);
            inv[qi] = 1.f / sum;
        }

        // PV with custom k-mapping k(lg,v) = (2ks+(v>>2))*16 + lg*4 + (v&3):
        // pf = in-lane repack of st; vf = two b64 reads matching the mapping.
        f32x4 ot[2][2];
        ot[0][0] = z; ot[0][1] = z; ot[1][0] = z; ot[1][1] = z;
        #pragma unroll
        for (int ks = 0; ks < 2; ++ks) {
            f16x8 pf[2], vf[2];
            #pragma unroll
            for (int qi = 0; qi < 2; ++qi) {
                f16x4v lo = __builtin_bit_cast(f16x4v, pack4h(st[2 * ks + 0][qi] * inv[qi]));
                f16x4v hi = __builtin_bit_cast(f16x4v, pack4h(st[2 * ks + 1][qi] * inv[qi]));
                pf[qi] = cat44(lo, hi);
            }
            #pragma unroll
            for (int dt = 0; dt < 2; ++dt) {
                const u16* vrow = Vh + (dt * 16 + m) * VT_S + lg * 4;
                f16x4v v0 = *(const f16x4v*)(vrow + (2 * ks + 0) * 16);
                f16x4v v1 = *(const f16x4v*)(vrow + (2 * ks + 1) * 16);
                vf[dt] = cat44(v0, v1);
            }
            #pragma unroll
            for (int qi = 0; qi < 2; ++qi)
                #pragma unroll
                for (int dt = 0; dt < 2; ++dt)
                    ot[qi][dt] = __builtin_amdgcn_mfma_f32_16x16x32_f16(pf[qi], vf[dt], ot[qi][dt], 0, 0, 0);
        }

        // O -> Ows [bw][pix][c] fp16 (lane=c-col, regs=q-rows)
        const size_t obase = (size_t)(b * 64 + win) * 16384;
        const int head = hq * 4 + hh;
        #pragma unroll
        for (int qi = 0; qi < 2; ++qi)
            #pragma unroll
            for (int dt = 0; dt < 2; ++dt) {
                int c = head * 32 + dt * 16 + m;
                #pragma unroll
                for (int r = 0; r < 4; ++r) {
                    int q = (2 * qh + qi) * 16 + lg * 4 + r;
                    Ows[obase + q * 256 + c] = f2hu(ot[qi][dt][r]);
                }
            }
    }
}

// -------- K2: out-projection, ROW-major blocks (coalesced 64B writes) --------
__global__ __launch_bounds__(512, 4)
void lsa_outproj_row(const u16* __restrict__ Ows, const u16* __restrict__ wo16k,
                     const float* __restrict__ b_out, float* __restrict__ out)
{
    __shared__ u16 Ot[64 * OT_S];    // 33792 B [64 px][264 c]

    const int tid = threadIdx.x;
    const int y = blockIdx.x, b = blockIdx.y;
    const int yq = y >> 3, py = y & 7;
    const int w = tid >> 6, m = tid & 15, lg = (tid >> 4) & 3;

    {
        const u16* slab = Ows + (size_t)(b * 64 + yq * 8) * 16384 + (py * 8) * 256;
        #pragma unroll
        for (int i = 0; i < 4; ++i) {
            int g = tid + i * 512;              // 2048 16B-chunks
            int wx = g >> 8, gg = g & 255;
            int lx = gg >> 5, c8 = (gg & 31) << 3;
            f16x8 v = *(const f16x8*)(slab + (size_t)wx * 16384 + lx * 256 + c8);
            *(f16x8*)(Ot + (wx * 8 + lx) * OT_S + c8) = v;
        }
    }
    __syncthreads();

    f32x4 oa[2][4];
    {
        const f32x4 z = {0.f, 0.f, 0.f, 0.f};
        #pragma unroll
        for (int mt = 0; mt < 2; ++mt)
            #pragma unroll
            for (int nt = 0; nt < 4; ++nt) oa[mt][nt] = z;
    }
    #pragma unroll
    for (int kt = 0; kt < 8; ++kt) {
        f16x8 wf[2], of[4];
        #pragma unroll
        for (int mt = 0; mt < 2; ++mt)
            wf[mt] = *(const f16x8*)(wo16k + kt * 8192 + (w * 32 + mt * 16 + m) * 32 + lg * 8);
        #pragma unroll
        for (int nt = 0; nt < 4; ++nt)
            of[nt] = *(const f16x8*)(Ot + (nt * 16 + m) * OT_S + kt * 32 + lg * 8);
        #pragma unroll
        for (int mt = 0; mt < 2; ++mt)
            #pragma unroll
            for (int nt = 0; nt < 4; ++nt)
                oa[mt][nt] = __builtin_amdgcn_mfma_f32_16x16x32_f16(wf[mt], of[nt], oa[mt][nt], 0, 0, 0);
    }
    // write out[b][oc][y][px]: 16 consecutive px per (oc) -> 64B segments
    float* ob = out + (size_t)b * 1048576 + y * 64;
    #pragma unroll
    for (int mt = 0; mt < 2; ++mt)
        #pragma unroll
        for (int nt = 0; nt < 4; ++nt) {
            int px = nt * 16 + m;
            #pragma unroll
            for (int r = 0; r < 4; ++r) {
                int oc = w * 32 + mt * 16 + lg * 4 + r;
                ob[(size_t)oc * 4096 + px] = oa[mt][nt][r] + b_out[oc];
            }
        }
}

extern "C" void kernel_launch(void* const* d_in, const int* in_sizes, int n_in,
                              void* d_out, int out_size, void* d_ws, size_t ws_size,
                              hipStream_t stream) {
    const float* x      = (const float*)d_in[0];
    const float* w_proj = (const float*)d_in[1];
    const float* pos    = (const float*)d_in[2];
    const float* w_out  = (const float*)d_in[3];
    const float* b_out  = (const float*)d_in[4];
    float* out = (float*)d_out;

    // d_ws: [0,32M) x_tw ; +32M w16k (384K) ; wo16k (128K) ; Ows (32M)
    u16* xtw   = (u16*)d_ws;
    u16* w16k  = (u16*)((char*)d_ws + 33554432);
    u16* wo16k = (u16*)((char*)d_ws + 33554432 + 393216);
    u16* Ows   = (u16*)((char*)d_ws + 33554432 + 393216 + 131072);

    prep<<<1536, 512, 0, stream>>>(x, w_proj, w_out, xtw, w16k, wo16k);
    lsa_qkv_attn_xt<<<dim3(128, 16), 512, 0, stream>>>(xtw, w16k, pos, Ows);
    lsa_outproj_row<<<dim3(64, 16), 512, 0, stream>>>(Ows, wo16k, b_out, out);
}